// Round 7
// baseline (388.929 us; speedup 1.0000x reference)
//
#include <hip/hip_runtime.h>
#include <hip/hip_bf16.h>
#include <cmath>

// Problem constants
constexpr int B  = 4;
constexpr int T  = 2048;
constexpr int C  = 768;
constexpr int H  = 12;
constexpr int Dh = 64;
constexpr int M  = B * T;          // 8192
constexpr int NQKV = 3 * C;        // 2304 fused QKV output width
constexpr int WS2  = C * C;        // 589824 elems per weight matrix

typedef short bf16x8 __attribute__((ext_vector_type(8)));
typedef short bf16x4 __attribute__((ext_vector_type(4)));
typedef float f32x4  __attribute__((ext_vector_type(4)));

__device__ inline short f2bf(float f) {   // fp32 -> bf16 round-nearest-even
    unsigned u = __float_as_uint(f);
    u += 0x7fffu + ((u >> 16) & 1u);
    return (short)(u >> 16);
}

__device__ inline unsigned pk_bf16(float a, float b) {  // packed pair (RNE)
    __hip_bfloat162 h = __float22bfloat162_rn(float2{a, b});
    return *(unsigned*)&h;
}

// ---------------------------------------------------------------------------
// Fused fp32 -> bf16 convert for x + all four weights (one launch).
// ---------------------------------------------------------------------------
constexpr size_t XE = (size_t)M * C;                // 6291456
constexpr size_t CV_TOTAL = XE + 4 * (size_t)WS2;   // 8650752

__global__ __launch_bounds__(256)
void convert_all(const float* __restrict__ x,  const float* __restrict__ Wq,
                 const float* __restrict__ Wk, const float* __restrict__ Wv,
                 const float* __restrict__ Wp,
                 short* __restrict__ xb, short* __restrict__ Wqkv,
                 short* __restrict__ Wpb) {
    size_t i = ((size_t)blockIdx.x * 256 + threadIdx.x) * 4;
    const float* src; short* dst; size_t off;
    if (i < XE)                        { src = x;  dst = xb;            off = i; }
    else if (i < XE + WS2)             { src = Wq; dst = Wqkv;          off = i - XE; }
    else if (i < XE + 2 * (size_t)WS2) { src = Wk; dst = Wqkv + WS2;    off = i - XE - WS2; }
    else if (i < XE + 3 * (size_t)WS2) { src = Wv; dst = Wqkv + 2 * WS2; off = i - XE - 2 * (size_t)WS2; }
    else                               { src = Wp; dst = Wpb;           off = i - XE - 3 * (size_t)WS2; }
    float4 v = *(const float4*)(src + off);
    bf16x4 o; o[0] = f2bf(v.x); o[1] = f2bf(v.y); o[2] = f2bf(v.z); o[3] = f2bf(v.w);
    *(bf16x4*)(dst + off) = o;
}

// ---------------------------------------------------------------------------
// bf16 MFMA GEMM, register-prefetch pipelined: Y[M,N] = A[M,K] @ W[N,K]^T
// BM x BN_ tile, BK=64 (32 MFMAs + 16 ds_read_b128 per barrier pair, 12
// K-iterations at K=768). Staging: global -> VGPR (issued right after
// barrier B of the PREVIOUS tile, so a full tile of compute hides the
// latency) -> LDS write at barrier A.
// ---------------------------------------------------------------------------
constexpr int BM = 128, BK2 = 64;

template<int BN_, int WMW, int WNW, int OUT_BF16>
__global__ __launch_bounds__(256)
void gemm_bt(const short* __restrict__ A, const short* __restrict__ W,
             const float* __restrict__ bias0, const float* __restrict__ bias1,
             const float* __restrict__ bias2,
             void* __restrict__ Yv, int Ndim, int Kdim) {
    constexpr int MT = BM / WMW / 16;
    constexpr int NT = BN_ / WNW / 16;
    constexpr int NA = BM * BK2 / 8;               // A int4 chunks (1024)
    constexpr int NTOT = (BM + BN_) * BK2 / 8;     // total int4 chunks
    constexpr int CH = NTOT / 256;                 // chunks per thread

    __shared__ short As[BM * BK2];
    __shared__ short Bs[BN_ * BK2];

    const int tid  = threadIdx.x;
    const int wave = tid >> 6;
    const int lane = tid & 63;
    const int li   = lane & 15;
    const int quad = lane >> 4;
    const int wm   = wave % WMW;
    const int wn   = wave / WMW;
    const int m0   = blockIdx.y * BM;
    const int n0   = blockIdx.x * BN_;

    f32x4 acc[MT][NT];
    #pragma unroll
    for (int i = 0; i < MT; ++i)
        #pragma unroll
        for (int j = 0; j < NT; ++j)
            acc[i][j] = (f32x4){0.f, 0.f, 0.f, 0.f};

    // Chunk mapping: idx = i*256+tid; 8 int4 chunks per 64-short row.
    // Precompute each chunk's global source pointer (advanced by BK2 per iter)
    const short* gsrc[CH];
    short* ldst[CH];
    #pragma unroll
    for (int i = 0; i < CH; ++i) {
        int idx = i * 256 + tid;
        if (idx < NA) {
            int row = idx >> 3, ch = idx & 7;
            gsrc[i] = A + (size_t)(m0 + row) * Kdim + ch * 8;
            ldst[i] = &As[row * BK2 + ch * 8];
        } else {
            int idx2 = idx - NA;
            int row = idx2 >> 3, ch = idx2 & 7;
            gsrc[i] = W + (size_t)(n0 + row) * Kdim + ch * 8;
            ldst[i] = &Bs[row * BK2 + ch * 8];
        }
    }

    // Prologue: prefetch tile 0.
    int4 pre[CH];
    #pragma unroll
    for (int i = 0; i < CH; ++i) pre[i] = *(const int4*)(gsrc[i]);

    for (int k0 = 0; k0 < Kdim; k0 += BK2) {
        __syncthreads();   // A: previous tile's fragment reads complete
        #pragma unroll
        for (int i = 0; i < CH; ++i) *(int4*)(ldst[i]) = pre[i];
        __syncthreads();   // B: staging visible

        // Issue next tile's loads now; a full tile of compute hides them.
        if (k0 + BK2 < Kdim) {
            #pragma unroll
            for (int i = 0; i < CH; ++i)
                pre[i] = *(const int4*)(gsrc[i] + k0 + BK2);
        }

        #pragma unroll
        for (int h = 0; h < 2; ++h) {
            bf16x8 af[MT], bfr[NT];
            #pragma unroll
            for (int t = 0; t < MT; ++t)
                af[t] = *(const bf16x8*)&As[(wm * MT * 16 + t * 16 + li) * BK2
                                            + h * 32 + quad * 8];
            #pragma unroll
            for (int t = 0; t < NT; ++t)
                bfr[t] = *(const bf16x8*)&Bs[(wn * NT * 16 + t * 16 + li) * BK2
                                             + h * 32 + quad * 8];
            #pragma unroll
            for (int i = 0; i < MT; ++i)
                #pragma unroll
                for (int j = 0; j < NT; ++j)
                    acc[i][j] = __builtin_amdgcn_mfma_f32_16x16x32_bf16(
                        af[i], bfr[j], acc[i][j], 0, 0, 0);
        }
    }

    float bb[NT];
    #pragma unroll
    for (int nt = 0; nt < NT; ++nt) bb[nt] = 0.f;
    if (bias0) {
        int s = n0 / C;
        const float* bp = (s == 0) ? bias0 : ((s == 1) ? bias1 : bias2);
        int nb = n0 % C;
        #pragma unroll
        for (int nt = 0; nt < NT; ++nt)
            bb[nt] = bp[nb + wn * NT * 16 + nt * 16 + li];
    }

    #pragma unroll
    for (int mt = 0; mt < MT; ++mt)
        #pragma unroll
        for (int nt = 0; nt < NT; ++nt)
            #pragma unroll
            for (int r = 0; r < 4; ++r) {
                int row = m0 + wm * MT * 16 + mt * 16 + quad * 4 + r;
                int col = n0 + wn * NT * 16 + nt * 16 + li;
                float v = acc[mt][nt][r] + bb[nt];
                if constexpr (OUT_BF16)
                    ((short*)Yv)[(size_t)row * Ndim + col] = f2bf(v);
                else
                    ((float*)Yv)[(size_t)row * Ndim + col] = v;
            }
}

// ---------------------------------------------------------------------------
// MFMA flash attention (unchanged from round 6: 100 us, MfmaUtil 24.5%).
// ---------------------------------------------------------------------------
constexpr int QT   = 128;
constexpr int KTT  = 64;
constexpr int LSTR = 72;
constexpr int PSTR = 72;
constexpr int QS   = NQKV;
constexpr float SOFT_SCALE = 0.18033688011112042f;  // (1/8) * log2(e)

__global__ __launch_bounds__(256)
void attn_fwd(const short* __restrict__ QKV, short* __restrict__ O) {
    __shared__ short Ks[KTT * LSTR];
    __shared__ short Vt[Dh * LSTR];
    __shared__ short Ps[4 * 32 * PSTR];

    const int tid  = threadIdx.x;
    const int wave = tid >> 6;
    const int lane = tid & 63;
    const int li   = lane & 15;
    const int quad = lane >> 4;
    const int b    = blockIdx.z;
    const int h    = blockIdx.y;
    const int qw   = blockIdx.x * QT + wave * 32;

    const short* Qg = QKV + (size_t)(b * T) * QS + h * Dh;
    const short* Kg = QKV + (size_t)(b * T) * QS + C + h * Dh;
    const short* Vg = QKV + (size_t)(b * T) * QS + 2 * C + h * Dh;

    bf16x8 qf[2][2];
    #pragma unroll
    for (int qb = 0; qb < 2; ++qb)
        #pragma unroll
        for (int dh = 0; dh < 2; ++dh)
            qf[qb][dh] = *(const bf16x8*)(Qg + (size_t)(qw + qb * 16 + li) * QS
                                             + dh * 32 + quad * 8);

    bf16x8 ones;
    #pragma unroll
    for (int i = 0; i < 8; ++i) ones[i] = (short)0x3F80;

    f32x4 oacc[2][4];
    #pragma unroll
    for (int qb = 0; qb < 2; ++qb)
        #pragma unroll
        for (int db = 0; db < 4; ++db)
            oacc[qb][db] = (f32x4){0.f, 0.f, 0.f, 0.f};
    f32x4 lacc[2] = {(f32x4){0.f, 0.f, 0.f, 0.f}, (f32x4){0.f, 0.f, 0.f, 0.f}};

    const int ktok = tid >> 3;
    const int kch  = tid & 7;
    const int vd2  = (tid & 31) * 2;
    const int vg   = tid >> 5;

    int4 kpre[2];
    unsigned vpre[8];
    kpre[0] = *(const int4*)(Kg + (size_t)(ktok)      * QS + kch * 8);
    kpre[1] = *(const int4*)(Kg + (size_t)(ktok + 32) * QS + kch * 8);
    #pragma unroll
    for (int t2 = 0; t2 < 8; ++t2)
        vpre[t2] = *(const unsigned*)(Vg + (size_t)(vg * 8 + t2) * QS + vd2);

    for (int kt = 0; kt < T; kt += KTT) {
        __syncthreads();

        *(int4*)&Ks[ktok * LSTR + kch * 8]        = kpre[0];
        *(int4*)&Ks[(ktok + 32) * LSTR + kch * 8] = kpre[1];
        {
            unsigned lo[4], hi[4];
            #pragma unroll
            for (int j = 0; j < 4; ++j) {
                lo[j] = __builtin_amdgcn_perm(vpre[2 * j + 1], vpre[2 * j], 0x05040100u);
                hi[j] = __builtin_amdgcn_perm(vpre[2 * j + 1], vpre[2 * j], 0x07060302u);
            }
            *(int4*)&Vt[vd2 * LSTR + vg * 8]       = make_int4(lo[0], lo[1], lo[2], lo[3]);
            *(int4*)&Vt[(vd2 + 1) * LSTR + vg * 8] = make_int4(hi[0], hi[1], hi[2], hi[3]);
        }
        __syncthreads();

        if (kt + KTT < T) {
            const size_t nb = kt + KTT;
            kpre[0] = *(const int4*)(Kg + (nb + ktok)      * QS + kch * 8);
            kpre[1] = *(const int4*)(Kg + (nb + ktok + 32) * QS + kch * 8);
            #pragma unroll
            for (int t2 = 0; t2 < 8; ++t2)
                vpre[t2] = *(const unsigned*)(Vg + (nb + vg * 8 + t2) * QS + vd2);
        }

        f32x4 st[2][4];
        #pragma unroll
        for (int kb = 0; kb < 4; ++kb) {
            bf16x8 kf0 = *(const bf16x8*)&Ks[(kb * 16 + li) * LSTR + quad * 8];
            bf16x8 kf1 = *(const bf16x8*)&Ks[(kb * 16 + li) * LSTR + 32 + quad * 8];
            #pragma unroll
            for (int qb = 0; qb < 2; ++qb) {
                f32x4 a = (f32x4){0.f, 0.f, 0.f, 0.f};
                a = __builtin_amdgcn_mfma_f32_16x16x32_bf16(kf0, qf[qb][0], a, 0, 0, 0);
                a = __builtin_amdgcn_mfma_f32_16x16x32_bf16(kf1, qf[qb][1], a, 0, 0, 0);
                st[qb][kb] = a;
            }
        }

        #pragma unroll
        for (int qb = 0; qb < 2; ++qb)
            #pragma unroll
            for (int kb = 0; kb < 4; ++kb) {
                float p0 = __builtin_amdgcn_exp2f(st[qb][kb][0] * SOFT_SCALE);
                float p1 = __builtin_amdgcn_exp2f(st[qb][kb][1] * SOFT_SCALE);
                float p2 = __builtin_amdgcn_exp2f(st[qb][kb][2] * SOFT_SCALE);
                float p3 = __builtin_amdgcn_exp2f(st[qb][kb][3] * SOFT_SCALE);
                uint2 w; w.x = pk_bf16(p0, p1); w.y = pk_bf16(p2, p3);
                *(uint2*)&Ps[(wave * 32 + qb * 16 + li) * PSTR + kb * 16 + quad * 4] = w;
            }
        __asm__ volatile("s_waitcnt lgkmcnt(0)" ::: "memory");

        #pragma unroll
        for (int kq = 0; kq < 2; ++kq) {
            bf16x8 pf[2];
            #pragma unroll
            for (int qb = 0; qb < 2; ++qb) {
                pf[qb] = *(const bf16x8*)&Ps[(wave * 32 + qb * 16 + li) * PSTR
                                             + kq * 32 + quad * 8];
                lacc[qb] = __builtin_amdgcn_mfma_f32_16x16x32_bf16(
                    pf[qb], ones, lacc[qb], 0, 0, 0);
            }
            #pragma unroll
            for (int db = 0; db < 4; ++db) {
                bf16x8 vf = *(const bf16x8*)&Vt[(db * 16 + li) * LSTR + kq * 32 + quad * 8];
                #pragma unroll
                for (int qb = 0; qb < 2; ++qb)
                    oacc[qb][db] = __builtin_amdgcn_mfma_f32_16x16x32_bf16(
                        pf[qb], vf, oacc[qb][db], 0, 0, 0);
            }
        }
    }

    #pragma unroll
    for (int qb = 0; qb < 2; ++qb)
        #pragma unroll
        for (int r = 0; r < 4; ++r) {
            float inv = 1.0f / lacc[qb][r];
            short* op = O + (size_t)(b * T + qw + qb * 16 + quad * 4 + r) * C
                          + h * Dh + li;
            #pragma unroll
            for (int db = 0; db < 4; ++db)
                op[db * 16] = f2bf(oacc[qb][db][r] * inv);
        }
}

// ---------------------------------------------------------------------------
// Launch
// ---------------------------------------------------------------------------
extern "C" void kernel_launch(void* const* d_in, const int* in_sizes, int n_in,
                              void* d_out, int out_size, void* d_ws, size_t ws_size,
                              hipStream_t stream) {
    (void)in_sizes; (void)n_in; (void)out_size; (void)ws_size;

    const float* x  = (const float*)d_in[0];
    const float* Wq = (const float*)d_in[1];
    const float* bq = (const float*)d_in[2];
    const float* Wk = (const float*)d_in[3];
    const float* bk = (const float*)d_in[4];
    const float* Wv = (const float*)d_in[5];
    const float* bv = (const float*)d_in[6];
    const float* Wp = (const float*)d_in[7];
    float* out = (float*)d_out;

    short* xb    = (short*)d_ws;                 // [M][C]      bf16
    short* Wqkv  = xb + (size_t)M * C;           // [2304][768] bf16
    short* Wpb   = Wqkv + 3 * (size_t)WS2;       // [768][768]  bf16
    short* QKVb  = Wpb + (size_t)WS2;            // [M][2304]   bf16
    short* AOb   = QKVb + (size_t)M * NQKV;      // [M][C]      bf16

    convert_all<<<dim3(CV_TOTAL / 1024), 256, 0, stream>>>(
        x, Wq, Wk, Wv, Wp, xb, Wqkv, Wpb);

    // Fused QKV projection: [8192 x 2304]
    gemm_bt<128, 2, 2, 1><<<dim3(NQKV / 128, M / BM), 256, 0, stream>>>(
        xb, Wqkv, bq, bk, bv, QKVb, NQKV, C);

    attn_fwd<<<dim3(T / QT, H, B), 256, 0, stream>>>(QKVb, AOb);

    // Output projection: [8192 x 768] fp32 out
    gemm_bt<64, 4, 1, 0><<<dim3(C / 64, M / BM), 256, 0, stream>>>(
        AOb, Wpb, nullptr, nullptr, nullptr, out, C, C);
}

// Round 8
// 243.631 us; speedup vs baseline: 1.5964x; 1.5964x over previous
//
#include <hip/hip_runtime.h>
#include <hip/hip_bf16.h>
#include <cmath>

// Problem constants
constexpr int B  = 4;
constexpr int T  = 2048;
constexpr int C  = 768;
constexpr int H  = 12;
constexpr int Dh = 64;
constexpr int M  = B * T;          // 8192
constexpr int NQKV = 3 * C;        // 2304 fused QKV output width
constexpr int WS2  = C * C;        // 589824 elems per weight matrix

typedef short bf16x8 __attribute__((ext_vector_type(8)));
typedef short bf16x4 __attribute__((ext_vector_type(4)));
typedef float f32x4  __attribute__((ext_vector_type(4)));

__device__ inline short f2bf(float f) {   // fp32 -> bf16 round-nearest-even
    unsigned u = __float_as_uint(f);
    u += 0x7fffu + ((u >> 16) & 1u);
    return (short)(u >> 16);
}

__device__ inline unsigned pk_bf16(float a, float b) {  // packed pair (RNE)
    __hip_bfloat162 h = __float22bfloat162_rn(float2{a, b});
    return *(unsigned*)&h;
}

// global(AS1) -> LDS(AS3) 16-byte async copy; HW writes ldsbase + lane*16.
typedef const __attribute__((address_space(1))) unsigned GU;
typedef __attribute__((address_space(3))) unsigned LU;
__device__ inline void async_copy16(const void* g, void* l) {
    __builtin_amdgcn_global_load_lds((GU*)g, (LU*)l, 16, 0, 0);
}

// ---------------------------------------------------------------------------
// Fused fp32 -> bf16 convert for x + all four weights (one launch).
// ---------------------------------------------------------------------------
constexpr size_t XE = (size_t)M * C;                // 6291456
constexpr size_t CV_TOTAL = XE + 4 * (size_t)WS2;   // 8650752

__global__ __launch_bounds__(256)
void convert_all(const float* __restrict__ x,  const float* __restrict__ Wq,
                 const float* __restrict__ Wk, const float* __restrict__ Wv,
                 const float* __restrict__ Wp,
                 short* __restrict__ xb, short* __restrict__ Wqkv,
                 short* __restrict__ Wpb) {
    size_t i = ((size_t)blockIdx.x * 256 + threadIdx.x) * 4;
    const float* src; short* dst; size_t off;
    if (i < XE)                        { src = x;  dst = xb;            off = i; }
    else if (i < XE + WS2)             { src = Wq; dst = Wqkv;          off = i - XE; }
    else if (i < XE + 2 * (size_t)WS2) { src = Wk; dst = Wqkv + WS2;    off = i - XE - WS2; }
    else if (i < XE + 3 * (size_t)WS2) { src = Wv; dst = Wqkv + 2 * WS2; off = i - XE - 2 * (size_t)WS2; }
    else                               { src = Wp; dst = Wpb;           off = i - XE - 3 * (size_t)WS2; }
    float4 v = *(const float4*)(src + off);
    bf16x4 o; o[0] = f2bf(v.x); o[1] = f2bf(v.y); o[2] = f2bf(v.z); o[3] = f2bf(v.w);
    *(bf16x4*)(dst + off) = o;
}

// ---------------------------------------------------------------------------
// bf16 MFMA GEMM: Y[M,N] = A[M,K] @ W[N,K]^T (+bias).
// r6 structure (async global_load_lds staging, proven layout) but staging
// TWO BK=32 k-halves per barrier pair -> 12 macro-iterations at K=768,
// 32 MFMAs per barrier pair instead of 16. No data VGPRs for staging
// (r7's register-prefetch spilled to scratch: 416 MB WRITE_SIZE).
// ---------------------------------------------------------------------------
constexpr int BM = 128;

template<int BN_, int WMW, int WNW, int OUT_BF16>
__global__ __launch_bounds__(256)
void gemm_bt(const short* __restrict__ A, const short* __restrict__ W,
             const float* __restrict__ bias0, const float* __restrict__ bias1,
             const float* __restrict__ bias2,
             void* __restrict__ Yv, int Ndim, int Kdim) {
    constexpr int MT  = BM / WMW / 16;
    constexpr int NT  = BN_ / WNW / 16;
    constexpr int NCH = (BM + BN_) / 16;     // 16-row chunks per k-half

    __shared__ short As[2][BM * 32];
    __shared__ short Bs[2][BN_ * 32];

    const int tid  = threadIdx.x;
    const int wave = tid >> 6;
    const int lane = tid & 63;
    const int li   = lane & 15;
    const int quad = lane >> 4;
    const int wm   = wave % WMW;
    const int wn   = wave / WMW;
    const int m0   = blockIdx.y * BM;
    const int n0   = blockIdx.x * BN_;

    f32x4 acc[MT][NT];
    #pragma unroll
    for (int i = 0; i < MT; ++i)
        #pragma unroll
        for (int j = 0; j < NT; ++j)
            acc[i][j] = (f32x4){0.f, 0.f, 0.f, 0.f};

    const int lrow = lane >> 2;          // 0..15 row within 16-row chunk
    const int lkof = (lane & 3) * 8;     // 16B chunk within 32-short half-row

    for (int k0 = 0; k0 < Kdim; k0 += 64) {
        __syncthreads();
        #pragma unroll
        for (int h = 0; h < 2; ++h)
            #pragma unroll
            for (int ii = 0; ii < NCH / 4; ++ii) {
                int c = ii * 4 + wave;
                if (c < BM / 16)
                    async_copy16(A + (size_t)(m0 + c * 16 + lrow) * Kdim
                                   + k0 + h * 32 + lkof,
                                 &As[h][c * 512]);
                else
                    async_copy16(W + (size_t)(n0 + (c - BM / 16) * 16 + lrow) * Kdim
                                   + k0 + h * 32 + lkof,
                                 &Bs[h][(c - BM / 16) * 512]);
            }
        __syncthreads();

        #pragma unroll
        for (int h = 0; h < 2; ++h) {
            bf16x8 af[MT], bfr[NT];
            #pragma unroll
            for (int t = 0; t < MT; ++t)
                af[t] = *(const bf16x8*)&As[h][(wm * MT * 16 + t * 16 + li) * 32 + quad * 8];
            #pragma unroll
            for (int t = 0; t < NT; ++t)
                bfr[t] = *(const bf16x8*)&Bs[h][(wn * NT * 16 + t * 16 + li) * 32 + quad * 8];
            #pragma unroll
            for (int i = 0; i < MT; ++i)
                #pragma unroll
                for (int j = 0; j < NT; ++j)
                    acc[i][j] = __builtin_amdgcn_mfma_f32_16x16x32_bf16(
                        af[i], bfr[j], acc[i][j], 0, 0, 0);
        }
    }

    float bb[NT];
    #pragma unroll
    for (int nt = 0; nt < NT; ++nt) bb[nt] = 0.f;
    if (bias0) {
        int s = n0 / C;
        const float* bp = (s == 0) ? bias0 : ((s == 1) ? bias1 : bias2);
        int nb = n0 % C;
        #pragma unroll
        for (int nt = 0; nt < NT; ++nt)
            bb[nt] = bp[nb + wn * NT * 16 + nt * 16 + li];
    }

    #pragma unroll
    for (int mt = 0; mt < MT; ++mt)
        #pragma unroll
        for (int nt = 0; nt < NT; ++nt)
            #pragma unroll
            for (int r = 0; r < 4; ++r) {
                int row = m0 + wm * MT * 16 + mt * 16 + quad * 4 + r;
                int col = n0 + wn * NT * 16 + nt * 16 + li;
                float v = acc[mt][nt][r] + bb[nt];
                if constexpr (OUT_BF16)
                    ((short*)Yv)[(size_t)row * Ndim + col] = f2bf(v);
                else
                    ((float*)Yv)[(size_t)row * Ndim + col] = v;
            }
}

// ---------------------------------------------------------------------------
// MFMA flash attention (unchanged from round 6: 100 us, MfmaUtil 24.5%).
// ---------------------------------------------------------------------------
constexpr int QT   = 128;
constexpr int KTT  = 64;
constexpr int LSTR = 72;
constexpr int PSTR = 72;
constexpr int QS   = NQKV;
constexpr float SOFT_SCALE = 0.18033688011112042f;  // (1/8) * log2(e)

__global__ __launch_bounds__(256)
void attn_fwd(const short* __restrict__ QKV, short* __restrict__ O) {
    __shared__ short Ks[KTT * LSTR];
    __shared__ short Vt[Dh * LSTR];
    __shared__ short Ps[4 * 32 * PSTR];

    const int tid  = threadIdx.x;
    const int wave = tid >> 6;
    const int lane = tid & 63;
    const int li   = lane & 15;
    const int quad = lane >> 4;
    const int b    = blockIdx.z;
    const int h    = blockIdx.y;
    const int qw   = blockIdx.x * QT + wave * 32;

    const short* Qg = QKV + (size_t)(b * T) * QS + h * Dh;
    const short* Kg = QKV + (size_t)(b * T) * QS + C + h * Dh;
    const short* Vg = QKV + (size_t)(b * T) * QS + 2 * C + h * Dh;

    bf16x8 qf[2][2];
    #pragma unroll
    for (int qb = 0; qb < 2; ++qb)
        #pragma unroll
        for (int dh = 0; dh < 2; ++dh)
            qf[qb][dh] = *(const bf16x8*)(Qg + (size_t)(qw + qb * 16 + li) * QS
                                             + dh * 32 + quad * 8);

    bf16x8 ones;
    #pragma unroll
    for (int i = 0; i < 8; ++i) ones[i] = (short)0x3F80;

    f32x4 oacc[2][4];
    #pragma unroll
    for (int qb = 0; qb < 2; ++qb)
        #pragma unroll
        for (int db = 0; db < 4; ++db)
            oacc[qb][db] = (f32x4){0.f, 0.f, 0.f, 0.f};
    f32x4 lacc[2] = {(f32x4){0.f, 0.f, 0.f, 0.f}, (f32x4){0.f, 0.f, 0.f, 0.f}};

    const int ktok = tid >> 3;
    const int kch  = tid & 7;
    const int vd2  = (tid & 31) * 2;
    const int vg   = tid >> 5;

    int4 kpre[2];
    unsigned vpre[8];
    kpre[0] = *(const int4*)(Kg + (size_t)(ktok)      * QS + kch * 8);
    kpre[1] = *(const int4*)(Kg + (size_t)(ktok + 32) * QS + kch * 8);
    #pragma unroll
    for (int t2 = 0; t2 < 8; ++t2)
        vpre[t2] = *(const unsigned*)(Vg + (size_t)(vg * 8 + t2) * QS + vd2);

    for (int kt = 0; kt < T; kt += KTT) {
        __syncthreads();

        *(int4*)&Ks[ktok * LSTR + kch * 8]        = kpre[0];
        *(int4*)&Ks[(ktok + 32) * LSTR + kch * 8] = kpre[1];
        {
            unsigned lo[4], hi[4];
            #pragma unroll
            for (int j = 0; j < 4; ++j) {
                lo[j] = __builtin_amdgcn_perm(vpre[2 * j + 1], vpre[2 * j], 0x05040100u);
                hi[j] = __builtin_amdgcn_perm(vpre[2 * j + 1], vpre[2 * j], 0x07060302u);
            }
            *(int4*)&Vt[vd2 * LSTR + vg * 8]       = make_int4(lo[0], lo[1], lo[2], lo[3]);
            *(int4*)&Vt[(vd2 + 1) * LSTR + vg * 8] = make_int4(hi[0], hi[1], hi[2], hi[3]);
        }
        __syncthreads();

        if (kt + KTT < T) {
            const size_t nb = kt + KTT;
            kpre[0] = *(const int4*)(Kg + (nb + ktok)      * QS + kch * 8);
            kpre[1] = *(const int4*)(Kg + (nb + ktok + 32) * QS + kch * 8);
            #pragma unroll
            for (int t2 = 0; t2 < 8; ++t2)
                vpre[t2] = *(const unsigned*)(Vg + (nb + vg * 8 + t2) * QS + vd2);
        }

        f32x4 st[2][4];
        #pragma unroll
        for (int kb = 0; kb < 4; ++kb) {
            bf16x8 kf0 = *(const bf16x8*)&Ks[(kb * 16 + li) * LSTR + quad * 8];
            bf16x8 kf1 = *(const bf16x8*)&Ks[(kb * 16 + li) * LSTR + 32 + quad * 8];
            #pragma unroll
            for (int qb = 0; qb < 2; ++qb) {
                f32x4 a = (f32x4){0.f, 0.f, 0.f, 0.f};
                a = __builtin_amdgcn_mfma_f32_16x16x32_bf16(kf0, qf[qb][0], a, 0, 0, 0);
                a = __builtin_amdgcn_mfma_f32_16x16x32_bf16(kf1, qf[qb][1], a, 0, 0, 0);
                st[qb][kb] = a;
            }
        }

        #pragma unroll
        for (int qb = 0; qb < 2; ++qb)
            #pragma unroll
            for (int kb = 0; kb < 4; ++kb) {
                float p0 = __builtin_amdgcn_exp2f(st[qb][kb][0] * SOFT_SCALE);
                float p1 = __builtin_amdgcn_exp2f(st[qb][kb][1] * SOFT_SCALE);
                float p2 = __builtin_amdgcn_exp2f(st[qb][kb][2] * SOFT_SCALE);
                float p3 = __builtin_amdgcn_exp2f(st[qb][kb][3] * SOFT_SCALE);
                uint2 w; w.x = pk_bf16(p0, p1); w.y = pk_bf16(p2, p3);
                *(uint2*)&Ps[(wave * 32 + qb * 16 + li) * PSTR + kb * 16 + quad * 4] = w;
            }
        __asm__ volatile("s_waitcnt lgkmcnt(0)" ::: "memory");

        #pragma unroll
        for (int kq = 0; kq < 2; ++kq) {
            bf16x8 pf[2];
            #pragma unroll
            for (int qb = 0; qb < 2; ++qb) {
                pf[qb] = *(const bf16x8*)&Ps[(wave * 32 + qb * 16 + li) * PSTR
                                             + kq * 32 + quad * 8];
                lacc[qb] = __builtin_amdgcn_mfma_f32_16x16x32_bf16(
                    pf[qb], ones, lacc[qb], 0, 0, 0);
            }
            #pragma unroll
            for (int db = 0; db < 4; ++db) {
                bf16x8 vf = *(const bf16x8*)&Vt[(db * 16 + li) * LSTR + kq * 32 + quad * 8];
                #pragma unroll
                for (int qb = 0; qb < 2; ++qb)
                    oacc[qb][db] = __builtin_amdgcn_mfma_f32_16x16x32_bf16(
                        pf[qb], vf, oacc[qb][db], 0, 0, 0);
            }
        }
    }

    #pragma unroll
    for (int qb = 0; qb < 2; ++qb)
        #pragma unroll
        for (int r = 0; r < 4; ++r) {
            float inv = 1.0f / lacc[qb][r];
            short* op = O + (size_t)(b * T + qw + qb * 16 + quad * 4 + r) * C
                          + h * Dh + li;
            #pragma unroll
            for (int db = 0; db < 4; ++db)
                op[db * 16] = f2bf(oacc[qb][db][r] * inv);
        }
}

// ---------------------------------------------------------------------------
// Launch
// ---------------------------------------------------------------------------
extern "C" void kernel_launch(void* const* d_in, const int* in_sizes, int n_in,
                              void* d_out, int out_size, void* d_ws, size_t ws_size,
                              hipStream_t stream) {
    (void)in_sizes; (void)n_in; (void)out_size; (void)ws_size;

    const float* x  = (const float*)d_in[0];
    const float* Wq = (const float*)d_in[1];
    const float* bq = (const float*)d_in[2];
    const float* Wk = (const float*)d_in[3];
    const float* bk = (const float*)d_in[4];
    const float* Wv = (const float*)d_in[5];
    const float* bv = (const float*)d_in[6];
    const float* Wp = (const float*)d_in[7];
    float* out = (float*)d_out;

    short* xb    = (short*)d_ws;                 // [M][C]      bf16
    short* Wqkv  = xb + (size_t)M * C;           // [2304][768] bf16
    short* Wpb   = Wqkv + 3 * (size_t)WS2;       // [768][768]  bf16
    short* QKVb  = Wpb + (size_t)WS2;            // [M][2304]   bf16
    short* AOb   = QKVb + (size_t)M * NQKV;      // [M][C]      bf16

    convert_all<<<dim3(CV_TOTAL / 1024), 256, 0, stream>>>(
        x, Wq, Wk, Wv, Wp, xb, Wqkv, Wpb);

    // Fused QKV projection: [8192 x 2304]
    gemm_bt<128, 2, 2, 1><<<dim3(NQKV / 128, M / BM), 256, 0, stream>>>(
        xb, Wqkv, bq, bk, bv, QKVb, NQKV, C);

    attn_fwd<<<dim3(T / QT, H, B), 256, 0, stream>>>(QKVb, AOb);

    // Output projection: [8192 x 768] fp32 out
    gemm_bt<64, 4, 1, 0><<<dim3(C / 64, M / BM), 256, 0, stream>>>(
        AOb, Wpb, nullptr, nullptr, nullptr, out, C, C);
}